// Round 1
// baseline (412.230 us; speedup 1.0000x reference)
//
#include <hip/hip_runtime.h>
#include <hip/hip_bf16.h>

#define N_HEADS 16
#define D_MODEL 1024
#define D_K     64
#define B_SZ    2
#define T_LEN   2048
#define M_ROWS  (B_SZ * T_LEN)   // 4096

typedef __bf16 bf16;
typedef __bf16 bf16x8 __attribute__((ext_vector_type(8)));
typedef float  f32x4  __attribute__((ext_vector_type(4)));

// ---------------------------------------------------------------------------
// Weight transpose + f32->bf16 convert: W [K=1024, N=1024] -> Wt [N, K] bf16
// ---------------------------------------------------------------------------
__global__ void wt_kernel(const float* __restrict__ W, bf16* __restrict__ Wt) {
    __shared__ float tile[32][33];
    const int tx = threadIdx.x;          // 0..31
    const int ty = threadIdx.y;          // 0..7
    const int x0 = blockIdx.x * 32;      // n
    const int y0 = blockIdx.y * 32;      // k
    for (int yy = ty; yy < 32; yy += 8)
        tile[yy][tx] = W[(size_t)(y0 + yy) * D_MODEL + x0 + tx];
    __syncthreads();
    for (int yy = ty; yy < 32; yy += 8)
        Wt[(size_t)(x0 + yy) * D_MODEL + y0 + tx] = (bf16)tile[tx][yy];
}

// ---------------------------------------------------------------------------
// GEMM: C[M=4096, N=1024] = A[M,K=1024] @ Bt[N,K]^T + bias
// MODE 0: write bf16 to head layout [B,H,T,dk]
// MODE 1: write bf16 to transposed head layout [B,H,dk,T]
// MODE 2: write f32 to [M,N] (final output)
// AF32: A operand is f32 (convert during staging) else bf16
// ---------------------------------------------------------------------------
template<int MODE, bool AF32>
__global__ __launch_bounds__(256) void gemm_kernel(
    const void* __restrict__ Ap, const bf16* __restrict__ Bt,
    const float* __restrict__ bias, void* __restrict__ Out)
{
    __shared__ bf16 As[128][40];   // +8 pad: 2-way max bank conflict, keeps 16B align
    __shared__ bf16 Bs[128][40];

    const int tid  = threadIdx.x;
    const int lane = tid & 63;
    const int w    = tid >> 6;
    const int wm   = w >> 1, wn = w & 1;
    const int g    = lane >> 4, c = lane & 15;
    const int m0   = blockIdx.x * 128, n0 = blockIdx.y * 128;

    const int srow = tid >> 1;           // 0..127
    const int scol = (tid & 1) * 16;     // 0 or 16

    f32x4 acc[4][4] = {};

    for (int k0 = 0; k0 < D_MODEL; k0 += 32) {
        // ---- stage A tile (128 x 32) ----
        bf16x8 wa0, wa1;
        if (AF32) {
            const float* A = (const float*)Ap;
            const float4* src = (const float4*)(A + (size_t)(m0 + srow) * D_MODEL + k0 + scol);
            float4 v0 = src[0], v1 = src[1], v2 = src[2], v3 = src[3];
            wa0[0]=(bf16)v0.x; wa0[1]=(bf16)v0.y; wa0[2]=(bf16)v0.z; wa0[3]=(bf16)v0.w;
            wa0[4]=(bf16)v1.x; wa0[5]=(bf16)v1.y; wa0[6]=(bf16)v1.z; wa0[7]=(bf16)v1.w;
            wa1[0]=(bf16)v2.x; wa1[1]=(bf16)v2.y; wa1[2]=(bf16)v2.z; wa1[3]=(bf16)v2.w;
            wa1[4]=(bf16)v3.x; wa1[5]=(bf16)v3.y; wa1[6]=(bf16)v3.z; wa1[7]=(bf16)v3.w;
        } else {
            const bf16* A = (const bf16*)Ap;
            const bf16x8* src = (const bf16x8*)(A + (size_t)(m0 + srow) * D_MODEL + k0 + scol);
            wa0 = src[0]; wa1 = src[1];
        }
        *(bf16x8*)&As[srow][scol]     = wa0;
        *(bf16x8*)&As[srow][scol + 8] = wa1;
        // ---- stage B tile (128 x 32) ----
        {
            const bf16x8* src = (const bf16x8*)(Bt + (size_t)(n0 + srow) * D_MODEL + k0 + scol);
            *(bf16x8*)&Bs[srow][scol]     = src[0];
            *(bf16x8*)&Bs[srow][scol + 8] = src[1];
        }
        __syncthreads();

        bf16x8 a[4], b[4];
        #pragma unroll
        for (int i = 0; i < 4; i++) a[i] = *(const bf16x8*)&As[wm*64 + i*16 + c][g*8];
        #pragma unroll
        for (int i = 0; i < 4; i++) b[i] = *(const bf16x8*)&Bs[wn*64 + i*16 + c][g*8];
        #pragma unroll
        for (int i = 0; i < 4; i++)
            #pragma unroll
            for (int j = 0; j < 4; j++)
                acc[i][j] = __builtin_amdgcn_mfma_f32_16x16x32_bf16(a[i], b[j], acc[i][j], 0, 0, 0);
        __syncthreads();
    }

    // ---- epilogue ----
    #pragma unroll
    for (int i = 0; i < 4; i++) {
        #pragma unroll
        for (int j = 0; j < 4; j++) {
            const int ncol = n0 + wn*64 + j*16 + c;
            const float bb = bias[ncol];
            #pragma unroll
            for (int r = 0; r < 4; r++) {
                const int mrow = m0 + wm*64 + i*16 + g*4 + r;
                const float y = acc[i][j][r] + bb;
                if (MODE == 2) {
                    ((float*)Out)[(size_t)mrow * D_MODEL + ncol] = y;
                } else {
                    const int b_ = mrow >> 11, t_ = mrow & (T_LEN - 1);
                    const int h_ = ncol >> 6,  d_ = ncol & (D_K - 1);
                    if (MODE == 0)
                        ((bf16*)Out)[(((size_t)(b_*N_HEADS + h_))*T_LEN + t_)*D_K + d_] = (bf16)y;
                    else
                        ((bf16*)Out)[(((size_t)(b_*N_HEADS + h_))*D_K + d_)*T_LEN + t_] = (bf16)y;
                }
            }
        }
    }
}

// ---------------------------------------------------------------------------
// Row L2 norms of head-layout bf16 tensor [rows, 64] -> f32 [rows]
// ---------------------------------------------------------------------------
__global__ void norm_kernel(const bf16* __restrict__ X, float* __restrict__ nrm, int nrows) {
    const int row  = blockIdx.x * 4 + (threadIdx.x >> 6);
    const int lane = threadIdx.x & 63;
    if (row >= nrows) return;
    float v = (float)X[(size_t)row * D_K + lane];
    float s = v * v;
    #pragma unroll
    for (int m = 1; m < 64; m <<= 1) s += __shfl_xor(s, m, 64);
    if (lane == 0) nrm[row] = sqrtf(s);
}

// ---------------------------------------------------------------------------
// Flash attention with (nq+nk)^2 score normalization.
// Grid: (B*H, T/64). Block: 256 (4 waves, 16 q-rows each).
// ---------------------------------------------------------------------------
__global__ __launch_bounds__(256) void attn_kernel(
    const bf16* __restrict__ qh, const bf16* __restrict__ kh, const bf16* __restrict__ vt,
    const float* __restrict__ nq, const float* __restrict__ nk,
    const float* __restrict__ alpha, bf16* __restrict__ ao)
{
    __shared__ bf16 plds[4][16][40];     // per-wave P tile, padded stride
    const int bh   = blockIdx.x;         // b*16 + h
    const int w    = threadIdx.x >> 6;
    const int lane = threadIdx.x & 63;
    const int g    = lane >> 4, c = lane & 15;
    const int q0   = blockIdx.y * 64 + w * 16;

    const bf16* Q  = qh + (size_t)bh * T_LEN * D_K;
    const bf16* K  = kh + (size_t)bh * T_LEN * D_K;
    const bf16* V  = vt + (size_t)bh * D_K * T_LEN;
    const float* NQ = nq + (size_t)bh * T_LEN;
    const float* NK = nk + (size_t)bh * T_LEN;
    const float a4 = alpha[bh & (N_HEADS - 1)] * 4.0f;

    // Q A-fragments: lane holds Q[q0 + c][g*8 .. g*8+7] (+32 for second K-slice)
    const bf16x8 aq0 = *(const bf16x8*)&Q[(size_t)(q0 + c) * D_K + g*8];
    const bf16x8 aq1 = *(const bf16x8*)&Q[(size_t)(q0 + c) * D_K + 32 + g*8];

    float nq_own[4];
    #pragma unroll
    for (int j = 0; j < 4; j++) nq_own[j] = NQ[q0 + g*4 + j];

    float mrun[4], ssum[4];
    f32x4 o[4] = {};
    #pragma unroll
    for (int j = 0; j < 4; j++) { mrun[j] = -1e30f; ssum[j] = 0.f; }

    for (int k0 = 0; k0 < T_LEN; k0 += 32) {
        f32x4 S[2];
        float nkc[2];
        #pragma unroll
        for (int cb = 0; cb < 2; cb++) {
            const bf16* Kb = &K[(size_t)(k0 + cb*16 + c) * D_K];
            const bf16x8 kb0 = *(const bf16x8*)&Kb[g*8];
            const bf16x8 kb1 = *(const bf16x8*)&Kb[32 + g*8];
            f32x4 s = {};
            s = __builtin_amdgcn_mfma_f32_16x16x32_bf16(aq0, kb0, s, 0, 0, 0);
            s = __builtin_amdgcn_mfma_f32_16x16x32_bf16(aq1, kb1, s, 0, 0, 0);
            S[cb] = s;
            nkc[cb] = NK[k0 + cb*16 + c];
        }
        // scale: alpha*4*qk / (nq+nk)^2
        float p[2][4];
        #pragma unroll
        for (int cb = 0; cb < 2; cb++)
            #pragma unroll
            for (int j = 0; j < 4; j++) {
                const float den = nq_own[j] + nkc[cb];
                p[cb][j] = a4 * S[cb][j] * __builtin_amdgcn_rcpf(den * den);
            }
        // online softmax
        float mnew[4], fac[4];
        #pragma unroll
        for (int j = 0; j < 4; j++) {
            float t = fmaxf(p[0][j], p[1][j]);
            t = fmaxf(t, __shfl_xor(t, 1, 64));
            t = fmaxf(t, __shfl_xor(t, 2, 64));
            t = fmaxf(t, __shfl_xor(t, 4, 64));
            t = fmaxf(t, __shfl_xor(t, 8, 64));
            mnew[j] = fmaxf(mrun[j], t);
            fac[j]  = __expf(mrun[j] - mnew[j]);
            mrun[j] = mnew[j];
        }
        #pragma unroll
        for (int j = 0; j < 4; j++) {
            float ps = 0.f;
            #pragma unroll
            for (int cb = 0; cb < 2; cb++) {
                p[cb][j] = __expf(p[cb][j] - mnew[j]);
                ps += p[cb][j];
            }
            ps += __shfl_xor(ps, 1, 64);
            ps += __shfl_xor(ps, 2, 64);
            ps += __shfl_xor(ps, 4, 64);
            ps += __shfl_xor(ps, 8, 64);
            ssum[j] = ssum[j] * fac[j] + ps;
            #pragma unroll
            for (int f = 0; f < 4; f++) o[f][j] *= fac[j];
        }
        // P -> LDS (C-layout write), reread as A-fragments
        #pragma unroll
        for (int cb = 0; cb < 2; cb++)
            #pragma unroll
            for (int j = 0; j < 4; j++)
                plds[w][g*4 + j][cb*16 + c] = (bf16)p[cb][j];
        const bf16x8 pf = *(const bf16x8*)&plds[w][c][g*8];
        // PV
        #pragma unroll
        for (int f = 0; f < 4; f++) {
            const bf16x8 vb = *(const bf16x8*)&V[(size_t)(f*16 + c) * T_LEN + k0 + g*8];
            o[f] = __builtin_amdgcn_mfma_f32_16x16x32_bf16(pf, vb, o[f], 0, 0, 0);
        }
    }

    // epilogue: divide by row sum, write bf16 [B,T,D]
    const int b_ = bh >> 4, h_ = bh & 15;
    #pragma unroll
    for (int j = 0; j < 4; j++) {
        const float inv = 1.0f / ssum[j];
        const int t_ = q0 + g*4 + j;
        #pragma unroll
        for (int f = 0; f < 4; f++)
            ao[((size_t)(b_*T_LEN + t_)) * D_MODEL + h_*D_K + f*16 + c] = (bf16)(o[f][j] * inv);
    }
}

// ---------------------------------------------------------------------------
extern "C" void kernel_launch(void* const* d_in, const int* in_sizes, int n_in,
                              void* d_out, int out_size, void* d_ws, size_t ws_size,
                              hipStream_t stream) {
    const float* q     = (const float*)d_in[0];
    const float* k     = (const float*)d_in[1];
    const float* v     = (const float*)d_in[2];
    const float* Wq    = (const float*)d_in[3];
    const float* bq    = (const float*)d_in[4];
    const float* Wk    = (const float*)d_in[5];
    const float* bk    = (const float*)d_in[6];
    const float* Wv    = (const float*)d_in[7];
    const float* bv    = (const float*)d_in[8];
    const float* Wo    = (const float*)d_in[9];
    const float* bo    = (const float*)d_in[10];
    const float* alpha = (const float*)d_in[11];

    char* ws = (char*)d_ws;
    const size_t WBYTES = (size_t)D_MODEL * D_MODEL * sizeof(bf16);   // 2MB
    const size_t HBYTES = (size_t)B_SZ * N_HEADS * T_LEN * D_K * sizeof(bf16); // 8MB
    const size_t NBYTES = (size_t)B_SZ * N_HEADS * T_LEN * sizeof(float);      // 256KB
    bf16* WtQ = (bf16*)ws;  ws += WBYTES;
    bf16* WtK = (bf16*)ws;  ws += WBYTES;
    bf16* WtV = (bf16*)ws;  ws += WBYTES;
    bf16* WtO = (bf16*)ws;  ws += WBYTES;
    bf16* qh  = (bf16*)ws;  ws += HBYTES;
    bf16* kh  = (bf16*)ws;  ws += HBYTES;
    bf16* vt  = (bf16*)ws;  ws += HBYTES;
    float* nq = (float*)ws; ws += NBYTES;
    float* nk = (float*)ws; ws += NBYTES;
    bf16* ao  = (bf16*)ws;  ws += (size_t)M_ROWS * D_MODEL * sizeof(bf16);

    const dim3 tb(32, 8);
    wt_kernel<<<dim3(32, 32), tb, 0, stream>>>(Wq, WtQ);
    wt_kernel<<<dim3(32, 32), tb, 0, stream>>>(Wk, WtK);
    wt_kernel<<<dim3(32, 32), tb, 0, stream>>>(Wv, WtV);
    wt_kernel<<<dim3(32, 32), tb, 0, stream>>>(Wo, WtO);

    const dim3 gg(M_ROWS / 128, D_MODEL / 128);
    gemm_kernel<0, true><<<gg, 256, 0, stream>>>(q, WtQ, bq, qh);
    gemm_kernel<0, true><<<gg, 256, 0, stream>>>(k, WtK, bk, kh);
    gemm_kernel<1, true><<<gg, 256, 0, stream>>>(v, WtV, bv, vt);

    const int nrows = B_SZ * N_HEADS * T_LEN;     // 65536
    norm_kernel<<<nrows / 4, 256, 0, stream>>>(qh, nq, nrows);
    norm_kernel<<<nrows / 4, 256, 0, stream>>>(kh, nk, nrows);

    attn_kernel<<<dim3(B_SZ * N_HEADS, T_LEN / 64), 256, 0, stream>>>(
        qh, kh, vt, nq, nk, alpha, ao);

    gemm_kernel<2, false><<<gg, 256, 0, stream>>>(ao, WtO, bo, d_out);
}

// Round 2
// 394.756 us; speedup vs baseline: 1.0443x; 1.0443x over previous
//
#include <hip/hip_runtime.h>
#include <hip/hip_bf16.h>

#define N_HEADS 16
#define D_MODEL 1024
#define D_K     64
#define B_SZ    2
#define T_LEN   2048
#define M_ROWS  (B_SZ * T_LEN)   // 4096

typedef __bf16 bf16;
typedef __bf16 bf16x4 __attribute__((ext_vector_type(4)));
typedef __bf16 bf16x8 __attribute__((ext_vector_type(8)));
typedef float  f32x4  __attribute__((ext_vector_type(4)));
typedef unsigned int u32;

// async global->LDS, 16B per lane. LDS dest = wave-uniform base + lane*16.
__device__ __forceinline__ void gload16(const bf16* g, bf16* l) {
    __builtin_amdgcn_global_load_lds(
        (const __attribute__((address_space(1))) u32*)g,
        (__attribute__((address_space(3))) u32*)l, 16, 0, 0);
}

// ---------------------------------------------------------------------------
// Weight transpose + f32->bf16: W [K,N] -> Wt [N,K] bf16
// ---------------------------------------------------------------------------
__global__ void wt_kernel(const float* __restrict__ W, bf16* __restrict__ Wt) {
    __shared__ float tile[32][33];
    const int tx = threadIdx.x, ty = threadIdx.y;
    const int x0 = blockIdx.x * 32, y0 = blockIdx.y * 32;
    for (int yy = ty; yy < 32; yy += 8)
        tile[yy][tx] = W[(size_t)(y0 + yy) * D_MODEL + x0 + tx];
    __syncthreads();
    for (int yy = ty; yy < 32; yy += 8)
        Wt[(size_t)(x0 + yy) * D_MODEL + y0 + tx] = (bf16)tile[tx][yy];
}

// ---------------------------------------------------------------------------
// f32 -> bf16 elementwise (4 elems/thread)
// ---------------------------------------------------------------------------
__global__ void conv_kernel(const float* __restrict__ X, bf16* __restrict__ Y) {
    const int i = blockIdx.x * 256 + threadIdx.x;
    const float4 v = ((const float4*)X)[i];
    bf16x4 y;
    y[0] = (bf16)v.x; y[1] = (bf16)v.y; y[2] = (bf16)v.z; y[3] = (bf16)v.w;
    ((bf16x4*)Y)[i] = y;
}

// ---------------------------------------------------------------------------
// GEMM: C[M,N] = A[M,K] @ Bt[N,K]^T + bias, A bf16, global_load_lds staging.
// MODE 0: bf16 out, head layout [B,H,T,dk]
// MODE 1: bf16 out, transposed head layout [B,H,dk,T] (computes C^T in-reg)
// MODE 2: f32 out [M,N]
// ---------------------------------------------------------------------------
template<int MODE>
__global__ __launch_bounds__(256) void gemm_kernel(
    const bf16* __restrict__ A, const bf16* __restrict__ Bt,
    const float* __restrict__ bias, void* __restrict__ Out)
{
    __shared__ bf16 As[128][32];   // linear: required by global_load_lds
    __shared__ bf16 Bs[128][32];

    const int tid  = threadIdx.x;
    const int lane = tid & 63;
    const int w    = tid >> 6;
    const int wm   = w >> 1, wn = w & 1;
    const int g    = lane >> 4, c = lane & 15;
    const int m0   = blockIdx.x * 128, n0 = blockIdx.y * 128;

    const int lr = lane >> 2;         // row within 16-row group
    const int lc = (lane & 3) * 8;    // elem col 0/8/16/24

    const bf16* Ag = A  + (size_t)(m0 + w*32 + lr) * D_MODEL + lc;
    const bf16* Bg = Bt + (size_t)(n0 + w*32 + lr) * D_MODEL + lc;
    bf16* Al0 = &As[w*32][0];
    bf16* Al1 = &As[w*32 + 16][0];
    bf16* Bl0 = &Bs[w*32][0];
    bf16* Bl1 = &Bs[w*32 + 16][0];

    f32x4 acc[4][4] = {};

    for (int k0 = 0; k0 < D_MODEL; k0 += 32) {
        gload16(Ag + k0,               Al0);
        gload16(Ag + 16*D_MODEL + k0,  Al1);
        gload16(Bg + k0,               Bl0);
        gload16(Bg + 16*D_MODEL + k0,  Bl1);
        __syncthreads();

        bf16x8 a[4], b[4];
        #pragma unroll
        for (int i = 0; i < 4; i++) a[i] = *(const bf16x8*)&As[wm*64 + i*16 + c][g*8];
        #pragma unroll
        for (int j = 0; j < 4; j++) b[j] = *(const bf16x8*)&Bs[wn*64 + j*16 + c][g*8];

        __builtin_amdgcn_s_setprio(1);
        #pragma unroll
        for (int i = 0; i < 4; i++)
            #pragma unroll
            for (int j = 0; j < 4; j++)
                acc[i][j] = (MODE == 1)
                    ? __builtin_amdgcn_mfma_f32_16x16x32_bf16(b[j], a[i], acc[i][j], 0, 0, 0)
                    : __builtin_amdgcn_mfma_f32_16x16x32_bf16(a[i], b[j], acc[i][j], 0, 0, 0);
        __builtin_amdgcn_s_setprio(0);
        __syncthreads();
    }

    #pragma unroll
    for (int i = 0; i < 4; i++)
        #pragma unroll
        for (int j = 0; j < 4; j++)
            #pragma unroll
            for (int r = 0; r < 4; r++) {
                if (MODE == 0) {
                    const int mrow = m0 + wm*64 + i*16 + g*4 + r;
                    const int ncol = n0 + wn*64 + j*16 + c;
                    const float y = acc[i][j][r] + bias[ncol];
                    const int b_ = mrow >> 11, t_ = mrow & (T_LEN - 1);
                    const int h_ = ncol >> 6,  d_ = ncol & (D_K - 1);
                    ((bf16*)Out)[(((size_t)(b_*N_HEADS + h_))*T_LEN + t_)*D_K + d_] = (bf16)y;
                } else if (MODE == 1) {
                    // acc holds C^T: row = n-local, col = m-local
                    const int nrow = n0 + wn*64 + j*16 + g*4 + r;
                    const int mcol = m0 + wm*64 + i*16 + c;
                    const float y = acc[i][j][r] + bias[nrow];
                    const int b_ = mcol >> 11, t_ = mcol & (T_LEN - 1);
                    const int h_ = nrow >> 6,  d_ = nrow & (D_K - 1);
                    ((bf16*)Out)[(((size_t)(b_*N_HEADS + h_))*D_K + d_)*T_LEN + t_] = (bf16)y;
                } else {
                    const int mrow = m0 + wm*64 + i*16 + g*4 + r;
                    const int ncol = n0 + wn*64 + j*16 + c;
                    ((float*)Out)[(size_t)mrow * D_MODEL + ncol] = acc[i][j][r] + bias[ncol];
                }
            }
}

// ---------------------------------------------------------------------------
// Row L2 norms of [rows, 64] bf16 -> f32 [rows]
// ---------------------------------------------------------------------------
__global__ void norm_kernel(const bf16* __restrict__ X, float* __restrict__ nrm, int nrows) {
    const int row  = blockIdx.x * 4 + (threadIdx.x >> 6);
    const int lane = threadIdx.x & 63;
    if (row >= nrows) return;
    float v = (float)X[(size_t)row * D_K + lane];
    float s = v * v;
    #pragma unroll
    for (int m = 1; m < 64; m <<= 1) s += __shfl_xor(s, m, 64);
    if (lane == 0) nrm[row] = sqrtf(s);
}

// ---------------------------------------------------------------------------
// Flash attention, swapped QK^T: lane owns q = lane&15 column, k lane-local.
// Grid: (B*H, T/64). Block 256 (4 waves, 16 q each). KVBLK = 64.
// ---------------------------------------------------------------------------
#define KVB 64

__global__ __launch_bounds__(256) void attn_kernel(
    const bf16* __restrict__ qh, const bf16* __restrict__ kh, const bf16* __restrict__ vt,
    const float* __restrict__ nq, const float* __restrict__ nk,
    const float* __restrict__ alpha, bf16* __restrict__ ao)
{
    __shared__ bf16 plds[4][16][72];     // per-wave P[q][k] tile, padded row
    const int bh   = blockIdx.x;
    const int w    = threadIdx.x >> 6;
    const int lane = threadIdx.x & 63;
    const int g    = lane >> 4, c = lane & 15;
    const int q0   = blockIdx.y * 64 + w * 16;
    const int myq  = q0 + c;

    const bf16* Q  = qh + (size_t)bh * T_LEN * D_K;
    const bf16* K  = kh + (size_t)bh * T_LEN * D_K;
    const bf16* V  = vt + (size_t)bh * D_K * T_LEN;
    const float* NK = nk + (size_t)bh * T_LEN;
    // fold 4*alpha and log2(e) so softmax runs in exp2 domain
    const float a4 = alpha[bh & (N_HEADS - 1)] * 4.0f * 1.44269504f;

    // Q as B-operand: lane holds Q[myq][g*8+e]
    const bf16x8 bq0 = *(const bf16x8*)&Q[(size_t)myq * D_K + g*8];
    const bf16x8 bq1 = *(const bf16x8*)&Q[(size_t)myq * D_K + 32 + g*8];
    const float nq_own = nq[(size_t)bh * T_LEN + myq];

    float mrun = -1e30f, ssum = 0.f;
    f32x4 o[4] = {};   // O^T: lane holds O[q=c][d = f*16 + g*4 + r]

    for (int k0 = 0; k0 < T_LEN; k0 += KVB) {
        // ---- S^T = K.Q^T : lane gets S[k0+cb*16+g*4+r][myq] ----
        f32x4 S[KVB/16];
        __builtin_amdgcn_s_setprio(1);
        #pragma unroll
        for (int cb = 0; cb < KVB/16; cb++) {
            const bf16* Kr = &K[(size_t)(k0 + cb*16 + c) * D_K];
            const bf16x8 ka = *(const bf16x8*)&Kr[g*8];
            const bf16x8 kb = *(const bf16x8*)&Kr[32 + g*8];
            f32x4 s = {};
            s = __builtin_amdgcn_mfma_f32_16x16x32_bf16(ka, bq0, s, 0, 0, 0);
            s = __builtin_amdgcn_mfma_f32_16x16x32_bf16(kb, bq1, s, 0, 0, 0);
            S[cb] = s;
        }
        __builtin_amdgcn_s_setprio(0);

        // ---- scale into log2 domain ----
        float p[KVB/16][4];
        #pragma unroll
        for (int cb = 0; cb < KVB/16; cb++) {
            const float4 nk4 = *(const float4*)&NK[k0 + cb*16 + g*4];
            const float nkr[4] = {nk4.x, nk4.y, nk4.z, nk4.w};
            #pragma unroll
            for (int r = 0; r < 4; r++) {
                const float den = nq_own + nkr[r];
                p[cb][r] = a4 * S[cb][r] * __builtin_amdgcn_rcpf(den * den);
            }
        }

        // ---- column max: register tree + 2 shfl over g ----
        float t0 = fmaxf(fmaxf(p[0][0], p[0][1]), fmaxf(p[0][2], p[0][3]));
        float t1 = fmaxf(fmaxf(p[1][0], p[1][1]), fmaxf(p[1][2], p[1][3]));
        float t2 = fmaxf(fmaxf(p[2][0], p[2][1]), fmaxf(p[2][2], p[2][3]));
        float t3 = fmaxf(fmaxf(p[3][0], p[3][1]), fmaxf(p[3][2], p[3][3]));
        float tm = fmaxf(fmaxf(t0, t1), fmaxf(t2, t3));
        tm = fmaxf(tm, __shfl_xor(tm, 16, 64));
        tm = fmaxf(tm, __shfl_xor(tm, 32, 64));
        const float mnew = fmaxf(mrun, tm);
        const float fac  = exp2f(mrun - mnew);
        mrun = mnew;

        // ---- exp2 + column sum ----
        float cs[KVB/16];
        #pragma unroll
        for (int cb = 0; cb < KVB/16; cb++) {
            #pragma unroll
            for (int r = 0; r < 4; r++) p[cb][r] = exp2f(p[cb][r] - mnew);
            cs[cb] = (p[cb][0] + p[cb][1]) + (p[cb][2] + p[cb][3]);
        }
        float ps = (cs[0] + cs[1]) + (cs[2] + cs[3]);
        ps += __shfl_xor(ps, 16, 64);
        ps += __shfl_xor(ps, 32, 64);
        ssum = ssum * fac + ps;

        #pragma unroll
        for (int f = 0; f < 4; f++)
            #pragma unroll
            for (int r = 0; r < 4; r++) o[f][r] *= fac;

        // ---- P[q][k] -> per-wave LDS (b64 writes), reread as B-frags ----
        #pragma unroll
        for (int cb = 0; cb < KVB/16; cb++) {
            bf16x4 pk;
            pk[0] = (bf16)p[cb][0]; pk[1] = (bf16)p[cb][1];
            pk[2] = (bf16)p[cb][2]; pk[3] = (bf16)p[cb][3];
            *(bf16x4*)&plds[w][c][cb*16 + g*4] = pk;
        }

        // ---- O^T += V^T . P^T ----
        __builtin_amdgcn_s_setprio(1);
        #pragma unroll
        for (int ks = 0; ks < KVB/32; ks++) {
            const bf16x8 pb = *(const bf16x8*)&plds[w][c][ks*32 + g*8];
            #pragma unroll
            for (int f = 0; f < 4; f++) {
                const bf16x8 vb = *(const bf16x8*)&V[(size_t)(f*16 + c)*T_LEN + k0 + ks*32 + g*8];
                o[f] = __builtin_amdgcn_mfma_f32_16x16x32_bf16(vb, pb, o[f], 0, 0, 0);
            }
        }
        __builtin_amdgcn_s_setprio(0);
    }

    // ---- epilogue: O[q=myq][d] / ssum -> ao [B,T,D] bf16 ----
    const int b_ = bh >> 4, h_ = bh & 15;
    const float inv = 1.0f / ssum;
    #pragma unroll
    for (int f = 0; f < 4; f++) {
        bf16x4 w4;
        #pragma unroll
        for (int r = 0; r < 4; r++) w4[r] = (bf16)(o[f][r] * inv);
        *(bf16x4*)&ao[((size_t)(b_*T_LEN + myq))*D_MODEL + h_*D_K + f*16 + g*4] = w4;
    }
}

// ---------------------------------------------------------------------------
extern "C" void kernel_launch(void* const* d_in, const int* in_sizes, int n_in,
                              void* d_out, int out_size, void* d_ws, size_t ws_size,
                              hipStream_t stream) {
    const float* q     = (const float*)d_in[0];
    const float* k     = (const float*)d_in[1];
    const float* v     = (const float*)d_in[2];
    const float* Wq    = (const float*)d_in[3];
    const float* bq    = (const float*)d_in[4];
    const float* Wk    = (const float*)d_in[5];
    const float* bk    = (const float*)d_in[6];
    const float* Wv    = (const float*)d_in[7];
    const float* bv    = (const float*)d_in[8];
    const float* Wo    = (const float*)d_in[9];
    const float* bo    = (const float*)d_in[10];
    const float* alpha = (const float*)d_in[11];

    char* ws = (char*)d_ws;
    const size_t WBYTES = (size_t)D_MODEL * D_MODEL * sizeof(bf16);                // 2MB
    const size_t HBYTES = (size_t)B_SZ * N_HEADS * T_LEN * D_K * sizeof(bf16);     // 8MB
    const size_t NBYTES = (size_t)B_SZ * N_HEADS * T_LEN * sizeof(float);          // 256KB
    bf16* WtQ = (bf16*)ws;  ws += WBYTES;
    bf16* WtK = (bf16*)ws;  ws += WBYTES;
    bf16* WtV = (bf16*)ws;  ws += WBYTES;
    bf16* WtO = (bf16*)ws;  ws += WBYTES;
    bf16* qh  = (bf16*)ws;  ws += HBYTES;
    bf16* kh  = (bf16*)ws;  ws += HBYTES;
    bf16* vt  = (bf16*)ws;  ws += HBYTES;
    float* nq = (float*)ws; ws += NBYTES;
    float* nk = (float*)ws; ws += NBYTES;
    bf16* ao  = (bf16*)ws;  ws += (size_t)M_ROWS * D_MODEL * sizeof(bf16);         // 8MB
    bf16* cb  = ao;  // alias: conv buffer dead before attn writes ao

    const dim3 tb(32, 8);
    wt_kernel<<<dim3(32, 32), tb, 0, stream>>>(Wq, WtQ);
    wt_kernel<<<dim3(32, 32), tb, 0, stream>>>(Wk, WtK);
    wt_kernel<<<dim3(32, 32), tb, 0, stream>>>(Wv, WtV);
    wt_kernel<<<dim3(32, 32), tb, 0, stream>>>(Wo, WtO);

    const dim3 gg(M_ROWS / 128, D_MODEL / 128);
    const int cgrid = M_ROWS * D_MODEL / 4 / 256;   // 4096

    conv_kernel<<<cgrid, 256, 0, stream>>>(q, cb);
    gemm_kernel<0><<<gg, 256, 0, stream>>>(cb, WtQ, bq, qh);
    conv_kernel<<<cgrid, 256, 0, stream>>>(k, cb);
    gemm_kernel<0><<<gg, 256, 0, stream>>>(cb, WtK, bk, kh);
    conv_kernel<<<cgrid, 256, 0, stream>>>(v, cb);
    gemm_kernel<1><<<gg, 256, 0, stream>>>(cb, WtV, bv, vt);

    const int nrows = B_SZ * N_HEADS * T_LEN;
    norm_kernel<<<nrows / 4, 256, 0, stream>>>(qh, nq, nrows);
    norm_kernel<<<nrows / 4, 256, 0, stream>>>(kh, nk, nrows);

    attn_kernel<<<dim3(B_SZ * N_HEADS, T_LEN / 64), 256, 0, stream>>>(
        qh, kh, vt, nq, nk, alpha, ao);

    gemm_kernel<2><<<gg, 256, 0, stream>>>(ao, WtO, bo, d_out);
}

// Round 3
// 251.554 us; speedup vs baseline: 1.6387x; 1.5693x over previous
//
#include <hip/hip_runtime.h>
#include <hip/hip_bf16.h>

#define N_HEADS 16
#define D_MODEL 1024
#define D_K     64
#define B_SZ    2
#define T_LEN   2048
#define M_ROWS  (B_SZ * T_LEN)   // 4096

typedef __bf16 bf16;
typedef __bf16 bf16x4 __attribute__((ext_vector_type(4)));
typedef __bf16 bf16x8 __attribute__((ext_vector_type(8)));
typedef float  f32x4  __attribute__((ext_vector_type(4)));
typedef unsigned int u32;

// async global->LDS, 16B per lane. LDS dest = wave-uniform base + lane*16.
__device__ __forceinline__ void gload16(const bf16* g, bf16* l) {
    __builtin_amdgcn_global_load_lds(
        (const __attribute__((address_space(1))) u32*)g,
        (__attribute__((address_space(3))) u32*)l, 16, 0, 0);
}

// ---------------------------------------------------------------------------
// Weight transpose + f32->bf16: W [K,N] -> Wt [N,K] bf16
// ---------------------------------------------------------------------------
__global__ void wt_kernel(const float* __restrict__ W, bf16* __restrict__ Wt) {
    __shared__ float tile[32][33];
    const int tx = threadIdx.x, ty = threadIdx.y;
    const int x0 = blockIdx.x * 32, y0 = blockIdx.y * 32;
    for (int yy = ty; yy < 32; yy += 8)
        tile[yy][tx] = W[(size_t)(y0 + yy) * D_MODEL + x0 + tx];
    __syncthreads();
    for (int yy = ty; yy < 32; yy += 8)
        Wt[(size_t)(x0 + yy) * D_MODEL + y0 + tx] = (bf16)tile[tx][yy];
}

// ---------------------------------------------------------------------------
// f32 -> bf16 elementwise (4 elems/thread)
// ---------------------------------------------------------------------------
__global__ void conv_kernel(const float* __restrict__ X, bf16* __restrict__ Y) {
    const int i = blockIdx.x * 256 + threadIdx.x;
    const float4 v = ((const float4*)X)[i];
    bf16x4 y;
    y[0] = (bf16)v.x; y[1] = (bf16)v.y; y[2] = (bf16)v.z; y[3] = (bf16)v.w;
    ((bf16x4*)Y)[i] = y;
}

// ---------------------------------------------------------------------------
// GEMM: C[M,N] = A[M,K] @ Bt[N,K]^T + bias, A bf16, global_load_lds staging.
// MODE 0: bf16 out, head layout [B,H,T,dk]
// MODE 1: bf16 out, transposed head layout [B,H,dk,T] (computes C^T in-reg)
// MODE 2: f32 out [M,N]
// ---------------------------------------------------------------------------
template<int MODE>
__global__ __launch_bounds__(256) void gemm_kernel(
    const bf16* __restrict__ A, const bf16* __restrict__ Bt,
    const float* __restrict__ bias, void* __restrict__ Out)
{
    __shared__ bf16 As[128][32];   // linear: required by global_load_lds
    __shared__ bf16 Bs[128][32];

    const int tid  = threadIdx.x;
    const int lane = tid & 63;
    const int w    = tid >> 6;
    const int wm   = w >> 1, wn = w & 1;
    const int g    = lane >> 4, c = lane & 15;
    const int m0   = blockIdx.x * 128, n0 = blockIdx.y * 128;

    const int lr = lane >> 2;         // row within 16-row group
    const int lc = (lane & 3) * 8;    // elem col 0/8/16/24

    const bf16* Ag = A  + (size_t)(m0 + w*32 + lr) * D_MODEL + lc;
    const bf16* Bg = Bt + (size_t)(n0 + w*32 + lr) * D_MODEL + lc;
    bf16* Al0 = &As[w*32][0];
    bf16* Al1 = &As[w*32 + 16][0];
    bf16* Bl0 = &Bs[w*32][0];
    bf16* Bl1 = &Bs[w*32 + 16][0];

    f32x4 acc[4][4] = {};

    for (int k0 = 0; k0 < D_MODEL; k0 += 32) {
        gload16(Ag + k0,               Al0);
        gload16(Ag + 16*D_MODEL + k0,  Al1);
        gload16(Bg + k0,               Bl0);
        gload16(Bg + 16*D_MODEL + k0,  Bl1);
        __syncthreads();

        bf16x8 a[4], b[4];
        #pragma unroll
        for (int i = 0; i < 4; i++) a[i] = *(const bf16x8*)&As[wm*64 + i*16 + c][g*8];
        #pragma unroll
        for (int j = 0; j < 4; j++) b[j] = *(const bf16x8*)&Bs[wn*64 + j*16 + c][g*8];

        __builtin_amdgcn_s_setprio(1);
        #pragma unroll
        for (int i = 0; i < 4; i++)
            #pragma unroll
            for (int j = 0; j < 4; j++)
                acc[i][j] = (MODE == 1)
                    ? __builtin_amdgcn_mfma_f32_16x16x32_bf16(b[j], a[i], acc[i][j], 0, 0, 0)
                    : __builtin_amdgcn_mfma_f32_16x16x32_bf16(a[i], b[j], acc[i][j], 0, 0, 0);
        __builtin_amdgcn_s_setprio(0);
        __syncthreads();
    }

    #pragma unroll
    for (int i = 0; i < 4; i++)
        #pragma unroll
        for (int j = 0; j < 4; j++)
            #pragma unroll
            for (int r = 0; r < 4; r++) {
                if (MODE == 0) {
                    const int mrow = m0 + wm*64 + i*16 + g*4 + r;
                    const int ncol = n0 + wn*64 + j*16 + c;
                    const float y = acc[i][j][r] + bias[ncol];
                    const int b_ = mrow >> 11, t_ = mrow & (T_LEN - 1);
                    const int h_ = ncol >> 6,  d_ = ncol & (D_K - 1);
                    ((bf16*)Out)[(((size_t)(b_*N_HEADS + h_))*T_LEN + t_)*D_K + d_] = (bf16)y;
                } else if (MODE == 1) {
                    // acc holds C^T: row = n-local, col = m-local
                    const int nrow = n0 + wn*64 + j*16 + g*4 + r;
                    const int mcol = m0 + wm*64 + i*16 + c;
                    const float y = acc[i][j][r] + bias[nrow];
                    const int b_ = mcol >> 11, t_ = mcol & (T_LEN - 1);
                    const int h_ = nrow >> 6,  d_ = nrow & (D_K - 1);
                    ((bf16*)Out)[(((size_t)(b_*N_HEADS + h_))*D_K + d_)*T_LEN + t_] = (bf16)y;
                } else {
                    const int mrow = m0 + wm*64 + i*16 + g*4 + r;
                    const int ncol = n0 + wn*64 + j*16 + c;
                    ((float*)Out)[(size_t)mrow * D_MODEL + ncol] = acc[i][j][r] + bias[ncol];
                }
            }
}

// ---------------------------------------------------------------------------
// Row L2 norms of [rows, 64] bf16 -> f32 [rows]
// ---------------------------------------------------------------------------
__global__ void norm_kernel(const bf16* __restrict__ X, float* __restrict__ nrm, int nrows) {
    const int row  = blockIdx.x * 4 + (threadIdx.x >> 6);
    const int lane = threadIdx.x & 63;
    if (row >= nrows) return;
    float v = (float)X[(size_t)row * D_K + lane];
    float s = v * v;
    #pragma unroll
    for (int m = 1; m < 64; m <<= 1) s += __shfl_xor(s, m, 64);
    if (lane == 0) nrm[row] = sqrtf(s);
}

// ---------------------------------------------------------------------------
// Flash attention v3: block-cooperative K/V LDS staging (double-buffered,
// XOR-swizzled via pre-swizzled global source), 32 q-rows/wave, XCD swizzle.
// Grid: 512 blocks (32 heads x 16 q-tiles of 128). Block 256 (4 waves).
// ---------------------------------------------------------------------------
#define KVB 64

__global__ __launch_bounds__(256, 3) void attn_kernel(
    const bf16* __restrict__ qh, const bf16* __restrict__ kh, const bf16* __restrict__ vt,
    const float* __restrict__ nq, const float* __restrict__ nk,
    const float* __restrict__ alpha, bf16* __restrict__ ao)
{
    __shared__ bf16 Ks[2][KVB * D_K];      // 8KB each, rows=k (64), 128B/row
    __shared__ bf16 Vs[2][KVB * D_K];      // 8KB each, rows=d (64), cols=k
    __shared__ bf16 plds[4][32][72];       // per-wave P[q][k], padded

    // XCD swizzle: hw bid%8 = XCD; give each XCD 64 consecutive logical blocks
    // (= 4 whole heads) so a head's K/V stays in that XCD's L2.
    const int bid     = blockIdx.x;
    const int logical = (bid & 7) * 64 + (bid >> 3);
    const int bh      = logical >> 4;            // head 0..31
    const int q0b     = (logical & 15) * 128;    // q-tile base

    const int w    = threadIdx.x >> 6;
    const int lane = threadIdx.x & 63;
    const int g    = lane >> 4, c = lane & 15;
    const int qw0  = q0b + w * 32;               // this wave's 32 q-rows
    const int sw   = (c & 7) << 4;               // read-side XOR swizzle (bytes)

    const bf16* Q  = qh + (size_t)bh * T_LEN * D_K;
    const bf16* K  = kh + (size_t)bh * T_LEN * D_K;
    const bf16* V  = vt + (size_t)bh * D_K * T_LEN;
    const float* NK = nk + (size_t)bh * T_LEN;
    const float a4 = alpha[bh & (N_HEADS - 1)] * 4.0f * 1.44269504f;

    // staging geometry: lane-slot s = w*128 + j*64 + lane; row = s>>3; 16B-unit
    // u = s&7 stored linearly; global unit = u ^ (row&7)  (involution)
    const int s0   = w * 128 + lane;
    const int row0 = s0 >> 3,        gb0 = ((s0 & 7) ^ (row0 & 7)) << 4;
    const int s1   = s0 + 64;
    const int row1 = s1 >> 3,        gb1 = ((s1 & 7) ^ (row1 & 7)) << 4;

    // Q fragments: qc in {0,1}, q = qw0 + qc*16 + c
    bf16x8 bq[2][2];
    float nq_own[2];
    #pragma unroll
    for (int qc = 0; qc < 2; qc++) {
        const bf16* Qr = &Q[(size_t)(qw0 + qc*16 + c) * D_K];
        bq[qc][0] = *(const bf16x8*)&Qr[g*8];
        bq[qc][1] = *(const bf16x8*)&Qr[32 + g*8];
        nq_own[qc] = nq[(size_t)bh * T_LEN + qw0 + qc*16 + c];
    }

    float mrun[2] = {-1e30f, -1e30f}, ssum[2] = {0.f, 0.f};
    f32x4 o[4][2] = {};    // O^T: lane owns q=qc*16+c col; d = f*16 + g*4 + r

    // prologue: stage tile 0 into buf 0
    {
        gload16((const bf16*)((const char*)&K[(size_t)row0 * D_K] + gb0), &Ks[0][s0 & ~63u ? (s0/64)*512 : 0] + 0);
    }
    // (rewritten below without the awkward expression)
    // -- real prologue --
    gload16((const bf16*)((const char*)&K[(size_t)row0 * D_K] + gb0), &Ks[0][(w*128 + 0*64) * 8]);
    gload16((const bf16*)((const char*)&V[(size_t)row0 * T_LEN] + gb0), &Vs[0][(w*128 + 0*64) * 8]);
    gload16((const bf16*)((const char*)&K[(size_t)row1 * D_K] + gb1), &Ks[0][(w*128 + 1*64) * 8]);
    gload16((const bf16*)((const char*)&V[(size_t)row1 * T_LEN] + gb1), &Vs[0][(w*128 + 1*64) * 8]);
    __syncthreads();

    const int NT = T_LEN / KVB;   // 32
    int cur = 0;
    for (int t = 0; t < NT; ++t) {
        const int k0 = t * KVB;

        // stage next tile into cur^1 (issue early; barrier at loop end drains)
        if (t + 1 < NT) {
            const int kn = k0 + KVB;
            gload16((const bf16*)((const char*)&K[(size_t)(kn + row0) * D_K] + gb0), &Ks[cur^1][(w*128 + 0*64) * 8]);
            gload16((const bf16*)((const char*)&V[(size_t)row0 * T_LEN + kn]  + gb0), &Vs[cur^1][(w*128 + 0*64) * 8]);
            gload16((const bf16*)((const char*)&K[(size_t)(kn + row1) * D_K] + gb1), &Ks[cur^1][(w*128 + 1*64) * 8]);
            gload16((const bf16*)((const char*)&V[(size_t)row1 * T_LEN + kn]  + gb1), &Vs[cur^1][(w*128 + 1*64) * 8]);
        }

        // ---- S^T = K.Q^T from LDS K tile ----
        f32x4 S[2][4] = {};
        __builtin_amdgcn_s_setprio(1);
        #pragma unroll
        for (int cb = 0; cb < 4; cb++) {
            const char* kbase = (const char*)&Ks[cur][(cb*16 + c) * D_K];
            const bf16x8 ka = *(const bf16x8*)(kbase + ((g*16) ^ sw));
            const bf16x8 kb = *(const bf16x8*)(kbase + ((64 + g*16) ^ sw));
            #pragma unroll
            for (int qc = 0; qc < 2; qc++) {
                S[qc][cb] = __builtin_amdgcn_mfma_f32_16x16x32_bf16(ka, bq[qc][0], S[qc][cb], 0, 0, 0);
                S[qc][cb] = __builtin_amdgcn_mfma_f32_16x16x32_bf16(kb, bq[qc][1], S[qc][cb], 0, 0, 0);
            }
        }
        __builtin_amdgcn_s_setprio(0);

        // ---- NK for this tile (shared across qc) ----
        float nkr[4][4];
        #pragma unroll
        for (int cb = 0; cb < 4; cb++) {
            const float4 nk4 = *(const float4*)&NK[k0 + cb*16 + g*4];
            nkr[cb][0] = nk4.x; nkr[cb][1] = nk4.y; nkr[cb][2] = nk4.z; nkr[cb][3] = nk4.w;
        }

        // ---- softmax per q-fragment ----
        float fac[2];
        #pragma unroll
        for (int qc = 0; qc < 2; qc++) {
            #pragma unroll
            for (int cb = 0; cb < 4; cb++)
                #pragma unroll
                for (int r = 0; r < 4; r++) {
                    const float den = nq_own[qc] + nkr[cb][r];
                    S[qc][cb][r] = a4 * S[qc][cb][r] * __builtin_amdgcn_rcpf(den * den);
                }
            float t0 = fmaxf(fmaxf(S[qc][0][0], S[qc][0][1]), fmaxf(S[qc][0][2], S[qc][0][3]));
            float t1 = fmaxf(fmaxf(S[qc][1][0], S[qc][1][1]), fmaxf(S[qc][1][2], S[qc][1][3]));
            float t2 = fmaxf(fmaxf(S[qc][2][0], S[qc][2][1]), fmaxf(S[qc][2][2], S[qc][2][3]));
            float t3 = fmaxf(fmaxf(S[qc][3][0], S[qc][3][1]), fmaxf(S[qc][3][2], S[qc][3][3]));
            float tm = fmaxf(fmaxf(t0, t1), fmaxf(t2, t3));
            tm = fmaxf(tm, __shfl_xor(tm, 16, 64));
            tm = fmaxf(tm, __shfl_xor(tm, 32, 64));
            const float mnew = fmaxf(mrun[qc], tm);
            fac[qc] = exp2f(mrun[qc] - mnew);
            mrun[qc] = mnew;

            float cs = 0.f;
            #pragma unroll
            for (int cb = 0; cb < 4; cb++) {
                #pragma unroll
                for (int r = 0; r < 4; r++) S[qc][cb][r] = exp2f(S[qc][cb][r] - mnew);
                cs += (S[qc][cb][0] + S[qc][cb][1]) + (S[qc][cb][2] + S[qc][cb][3]);
            }
            cs += __shfl_xor(cs, 16, 64);
            cs += __shfl_xor(cs, 32, 64);
            ssum[qc] = ssum[qc] * fac[qc] + cs;

            // P -> per-wave LDS rows qc*16+c
            #pragma unroll
            for (int cb = 0; cb < 4; cb++) {
                bf16x4 pk;
                pk[0] = (bf16)S[qc][cb][0]; pk[1] = (bf16)S[qc][cb][1];
                pk[2] = (bf16)S[qc][cb][2]; pk[3] = (bf16)S[qc][cb][3];
                *(bf16x4*)&plds[w][qc*16 + c][cb*16 + g*4] = pk;
            }
        }

        // ---- rescale O ----
        #pragma unroll
        for (int f = 0; f < 4; f++)
            #pragma unroll
            for (int qc = 0; qc < 2; qc++)
                #pragma unroll
                for (int r = 0; r < 4; r++) o[f][qc][r] *= fac[qc];

        // ---- O^T += V^T . P^T from LDS V tile ----
        __builtin_amdgcn_s_setprio(1);
        #pragma unroll
        for (int ks = 0; ks < 2; ks++) {
            const bf16x8 pb0 = *(const bf16x8*)&plds[w][c]     [ks*32 + g*8];
            const bf16x8 pb1 = *(const bf16x8*)&plds[w][16 + c][ks*32 + g*8];
            #pragma unroll
            for (int f = 0; f < 4; f++) {
                const char* vbase = (const char*)&Vs[cur][(f*16 + c) * D_K];
                const bf16x8 vb = *(const bf16x8*)(vbase + ((ks*64 + g*16) ^ sw));
                o[f][0] = __builtin_amdgcn_mfma_f32_16x16x32_bf16(vb, pb0, o[f][0], 0, 0, 0);
                o[f][1] = __builtin_amdgcn_mfma_f32_16x16x32_bf16(vb, pb1, o[f][1], 0, 0, 0);
            }
        }
        __builtin_amdgcn_s_setprio(0);

        __syncthreads();   // drains staging vmcnt + all waves done with cur
        cur ^= 1;
    }

    // ---- epilogue: O[q][d] / ssum -> ao [B,T,D] bf16 ----
    const int b_ = bh >> 4, h_ = bh & 15;
    #pragma unroll
    for (int qc = 0; qc < 2; qc++) {
        const float inv = 1.0f / ssum[qc];
        const int myq = qw0 + qc*16 + c;
        #pragma unroll
        for (int f = 0; f < 4; f++) {
            bf16x4 w4;
            #pragma unroll
            for (int r = 0; r < 4; r++) w4[r] = (bf16)(o[f][qc][r] * inv);
            *(bf16x4*)&ao[((size_t)(b_*T_LEN + myq))*D_MODEL + h_*D_K + f*16 + g*4] = w4;
        }
    }
}

// ---------------------------------------------------------------------------
extern "C" void kernel_launch(void* const* d_in, const int* in_sizes, int n_in,
                              void* d_out, int out_size, void* d_ws, size_t ws_size,
                              hipStream_t stream) {
    const float* q     = (const float*)d_in[0];
    const float* k     = (const float*)d_in[1];
    const float* v     = (const float*)d_in[2];
    const float* Wq    = (const float*)d_in[3];
    const float* bq    = (const float*)d_in[4];
    const float* Wk    = (const float*)d_in[5];
    const float* bk    = (const float*)d_in[6];
    const float* Wv    = (const float*)d_in[7];
    const float* bv    = (const float*)d_in[8];
    const float* Wo    = (const float*)d_in[9];
    const float* bo    = (const float*)d_in[10];
    const float* alpha = (const float*)d_in[11];

    char* ws = (char*)d_ws;
    const size_t WBYTES = (size_t)D_MODEL * D_MODEL * sizeof(bf16);                // 2MB
    const size_t HBYTES = (size_t)B_SZ * N_HEADS * T_LEN * D_K * sizeof(bf16);     // 8MB
    const size_t NBYTES = (size_t)B_SZ * N_HEADS * T_LEN * sizeof(float);          // 256KB
    bf16* WtQ = (bf16*)ws;  ws += WBYTES;
    bf16* WtK = (bf16*)ws;  ws += WBYTES;
    bf16* WtV = (bf16*)ws;  ws += WBYTES;
    bf16* WtO = (bf16*)ws;  ws += WBYTES;
    bf16* qh  = (bf16*)ws;  ws += HBYTES;
    bf16* kh  = (bf16*)ws;  ws += HBYTES;
    bf16* vt  = (bf16*)ws;  ws += HBYTES;
    float* nq = (float*)ws; ws += NBYTES;
    float* nk = (float*)ws; ws += NBYTES;
    bf16* ao  = (bf16*)ws;  ws += (size_t)M_ROWS * D_MODEL * sizeof(bf16);         // 8MB
    bf16* cb  = ao;  // alias: conv buffer dead before attn writes ao

    const dim3 tb(32, 8);
    wt_kernel<<<dim3(32, 32), tb, 0, stream>>>(Wq, WtQ);
    wt_kernel<<<dim3(32, 32), tb, 0, stream>>>(Wk, WtK);
    wt_kernel<<<dim3(32, 32), tb, 0, stream>>>(Wv, WtV);
    wt_kernel<<<dim3(32, 32), tb, 0, stream>>>(Wo, WtO);

    const dim3 gg(M_ROWS / 128, D_MODEL / 128);
    const int cgrid = M_ROWS * D_MODEL / 4 / 256;   // 4096

    conv_kernel<<<cgrid, 256, 0, stream>>>(q, cb);
    gemm_kernel<0><<<gg, 256, 0, stream>>>(cb, WtQ, bq, qh);
    conv_kernel<<<cgrid, 256, 0, stream>>>(k, cb);
    gemm_kernel<0><<<gg, 256, 0, stream>>>(cb, WtK, bk, kh);
    conv_kernel<<<cgrid, 256, 0, stream>>>(v, cb);
    gemm_kernel<1><<<gg, 256, 0, stream>>>(cb, WtV, bv, vt);

    const int nrows = B_SZ * N_HEADS * T_LEN;
    norm_kernel<<<nrows / 4, 256, 0, stream>>>(qh, nq, nrows);
    norm_kernel<<<nrows / 4, 256, 0, stream>>>(kh, nk, nrows);

    attn_kernel<<<512, 256, 0, stream>>>(qh, kh, vt, nq, nk, alpha, ao);

    gemm_kernel<2><<<gg, 256, 0, stream>>>(ao, WtO, bo, d_out);
}

// Round 5
// 192.824 us; speedup vs baseline: 2.1379x; 1.3046x over previous
//
#include <hip/hip_runtime.h>
#include <hip/hip_bf16.h>

#define N_HEADS 16
#define D_MODEL 1024
#define D_K     64
#define B_SZ    2
#define T_LEN   2048
#define M_ROWS  (B_SZ * T_LEN)   // 4096

typedef __bf16 bf16;
typedef __bf16 bf16x4 __attribute__((ext_vector_type(4)));
typedef __bf16 bf16x8 __attribute__((ext_vector_type(8)));
typedef float  f32x4  __attribute__((ext_vector_type(4)));
typedef unsigned int u32;

// async global->LDS, 16B per lane. LDS dest = wave-uniform base + lane*16.
__device__ __forceinline__ void gload16(const bf16* g, bf16* l) {
    __builtin_amdgcn_global_load_lds(
        (const __attribute__((address_space(1))) u32*)g,
        (__attribute__((address_space(3))) u32*)l, 16, 0, 0);
}

// ---------------------------------------------------------------------------
// Weight transpose + f32->bf16 (z selects which W): W [K,N] -> Wt [N,K] bf16
// ---------------------------------------------------------------------------
__global__ void wt_kernel(const float* __restrict__ W0, const float* __restrict__ W1,
                          const float* __restrict__ W2, const float* __restrict__ W3,
                          bf16* __restrict__ T0, bf16* __restrict__ T1,
                          bf16* __restrict__ T2, bf16* __restrict__ T3) {
    __shared__ float tile[32][33];
    const int z = blockIdx.z;
    const float* W = (z == 0) ? W0 : (z == 1) ? W1 : (z == 2) ? W2 : W3;
    bf16* Wt       = (z == 0) ? T0 : (z == 1) ? T1 : (z == 2) ? T2 : T3;
    const int tx = threadIdx.x, ty = threadIdx.y;
    const int x0 = blockIdx.x * 32, y0 = blockIdx.y * 32;
    for (int yy = ty; yy < 32; yy += 8)
        tile[yy][tx] = W[(size_t)(y0 + yy) * D_MODEL + x0 + tx];
    __syncthreads();
    for (int yy = ty; yy < 32; yy += 8)
        Wt[(size_t)(x0 + yy) * D_MODEL + y0 + tx] = (bf16)tile[tx][yy];
}

// ---------------------------------------------------------------------------
// Fused QKV projection: z in {0,1,2} picks (A, Wt, bias, Out, layout).
// C[4096,1024] = A_f32 @ Wt^T + bias.  z<2: head layout [B,H,T,dk].
// z==2: transposed head layout [B,H,dk,T] via in-register C^T (swapped mfma).
// A staged f32->bf16 in registers; B staged via global_load_lds.
// ---------------------------------------------------------------------------
__global__ __launch_bounds__(256, 3) void proj_kernel(
    const float* __restrict__ qf, const float* __restrict__ kf, const float* __restrict__ vf,
    const bf16* __restrict__ WtQ, const bf16* __restrict__ WtK, const bf16* __restrict__ WtV,
    const float* __restrict__ bqp, const float* __restrict__ bkp, const float* __restrict__ bvp,
    bf16* __restrict__ qh, bf16* __restrict__ kh, bf16* __restrict__ vt)
{
    __shared__ bf16 As[128][40];   // padded (80B rows, 16B-aligned)
    __shared__ bf16 Bs[128][32];   // linear (gload16 target)

    const int z = blockIdx.z;
    const float* A    = (z == 0) ? qf  : (z == 1) ? kf  : vf;
    const bf16*  Bt   = (z == 0) ? WtQ : (z == 1) ? WtK : WtV;
    const float* bias = (z == 0) ? bqp : (z == 1) ? bkp : bvp;
    bf16* Out         = (z == 0) ? qh  : (z == 1) ? kh  : vt;

    const int tid = threadIdx.x, lane = tid & 63, w = tid >> 6;
    const int wm = w >> 1, wn = w & 1, g = lane >> 4, c = lane & 15;
    const int m0 = blockIdx.x * 128, n0 = blockIdx.y * 128;

    const int arow = tid >> 1, acol = (tid & 1) * 16;
    const int brow = tid >> 2, bcol = (tid & 3) * 8;

    const float* Ag = A  + (size_t)(m0 + arow) * D_MODEL + acol;
    const bf16*  Bg = Bt + (size_t)(n0 + brow) * D_MODEL + bcol;
    bf16* Bl0 = &Bs[w * 16][0];
    bf16* Bl1 = &Bs[64 + w * 16][0];

    f32x4 acc[4][4] = {};

    for (int k0 = 0; k0 < D_MODEL; k0 += 32) {
        gload16(Bg + k0, Bl0);
        gload16(Bg + (size_t)64 * D_MODEL + k0, Bl1);
        const float4* asrc = (const float4*)(Ag + k0);
        float4 v0 = asrc[0], v1 = asrc[1], v2 = asrc[2], v3 = asrc[3];
        bf16x8 wa0, wa1;
        wa0[0]=(bf16)v0.x; wa0[1]=(bf16)v0.y; wa0[2]=(bf16)v0.z; wa0[3]=(bf16)v0.w;
        wa0[4]=(bf16)v1.x; wa0[5]=(bf16)v1.y; wa0[6]=(bf16)v1.z; wa0[7]=(bf16)v1.w;
        wa1[0]=(bf16)v2.x; wa1[1]=(bf16)v2.y; wa1[2]=(bf16)v2.z; wa1[3]=(bf16)v2.w;
        wa1[4]=(bf16)v3.x; wa1[5]=(bf16)v3.y; wa1[6]=(bf16)v3.z; wa1[7]=(bf16)v3.w;
        *(bf16x8*)&As[arow][acol]     = wa0;
        *(bf16x8*)&As[arow][acol + 8] = wa1;
        __syncthreads();

        bf16x8 a[4], b[4];
        #pragma unroll
        for (int i = 0; i < 4; i++) a[i] = *(const bf16x8*)&As[wm*64 + i*16 + c][g*8];
        #pragma unroll
        for (int j = 0; j < 4; j++) b[j] = *(const bf16x8*)&Bs[wn*64 + j*16 + c][g*8];

        __builtin_amdgcn_s_setprio(1);
        if (z != 2) {
            #pragma unroll
            for (int i = 0; i < 4; i++)
                #pragma unroll
                for (int j = 0; j < 4; j++)
                    acc[i][j] = __builtin_amdgcn_mfma_f32_16x16x32_bf16(a[i], b[j], acc[i][j], 0, 0, 0);
        } else {
            #pragma unroll
            for (int i = 0; i < 4; i++)
                #pragma unroll
                for (int j = 0; j < 4; j++)
                    acc[i][j] = __builtin_amdgcn_mfma_f32_16x16x32_bf16(b[j], a[i], acc[i][j], 0, 0, 0);
        }
        __builtin_amdgcn_s_setprio(0);
        __syncthreads();
    }

    #pragma unroll
    for (int i = 0; i < 4; i++)
        #pragma unroll
        for (int j = 0; j < 4; j++)
            #pragma unroll
            for (int r = 0; r < 4; r++) {
                if (z != 2) {
                    const int mrow = m0 + wm*64 + i*16 + g*4 + r;
                    const int ncol = n0 + wn*64 + j*16 + c;
                    const float y = acc[i][j][r] + bias[ncol];
                    const int b_ = mrow >> 11, t_ = mrow & (T_LEN - 1);
                    const int h_ = ncol >> 6,  d_ = ncol & (D_K - 1);
                    Out[(((size_t)(b_*N_HEADS + h_))*T_LEN + t_)*D_K + d_] = (bf16)y;
                } else {
                    const int nrow = n0 + wn*64 + j*16 + g*4 + r;
                    const int mcol = m0 + wm*64 + i*16 + c;
                    const float y = acc[i][j][r] + bias[nrow];
                    const int b_ = mcol >> 11, t_ = mcol & (T_LEN - 1);
                    const int h_ = nrow >> 6,  d_ = nrow & (D_K - 1);
                    Out[(((size_t)(b_*N_HEADS + h_))*D_K + d_)*T_LEN + t_] = (bf16)y;
                }
            }
}

// ---------------------------------------------------------------------------
// Row L2 norms: y=0 -> qh->nq, y=1 -> kh->nk
// ---------------------------------------------------------------------------
__global__ void norm_kernel(const bf16* __restrict__ qh, const bf16* __restrict__ kh,
                            float* __restrict__ nq, float* __restrict__ nk, int nrows) {
    const bf16* X = blockIdx.y ? kh : qh;
    float* O      = blockIdx.y ? nk : nq;
    const int row  = blockIdx.x * 4 + (threadIdx.x >> 6);
    const int lane = threadIdx.x & 63;
    if (row >= nrows) return;
    float v = (float)X[(size_t)row * D_K + lane];
    float s = v * v;
    #pragma unroll
    for (int m = 1; m < 64; m <<= 1) s += __shfl_xor(s, m, 64);
    if (lane == 0) O[row] = sqrtf(s);
}

// ---------------------------------------------------------------------------
// Flash attention v4: fixed-max softmax (|score| <= alpha by Cauchy-Schwarz),
// MFMA row-sum via ones-operand, 8 waves/block, double-buffered K/V LDS with
// XOR swizzle (pre-swizzled global source), XCD-aware block mapping.
// Grid: 512 blocks (32 heads x 16 q-tiles of 128). Block 512 (8 waves, 16 q).
// ---------------------------------------------------------------------------
#define KVB 64

__global__ __launch_bounds__(512, 4) void attn_kernel(
    const bf16* __restrict__ qh, const bf16* __restrict__ kh, const bf16* __restrict__ vt,
    const float* __restrict__ nq, const float* __restrict__ nk,
    const float* __restrict__ alpha, bf16* __restrict__ ao)
{
    __shared__ bf16 Ks[2][KVB * D_K];      // 8KB each
    __shared__ bf16 Vs[2][KVB * D_K];      // 8KB each
    __shared__ bf16 plds[8][16][72];       // per-wave P[q][k], 144B rows

    const int bid     = blockIdx.x;
    const int logical = (bid & 7) * 64 + (bid >> 3);   // 4 heads per XCD
    const int bh      = logical >> 4;
    const int q0b     = (logical & 15) * 128;

    const int tid  = threadIdx.x;
    const int w    = tid >> 6;
    const int lane = tid & 63;
    const int g    = lane >> 4, c = lane & 15;
    const int myq  = q0b + w * 16 + c;
    const int sw   = (c & 7) << 4;         // read-side XOR swizzle (bytes)

    // staging geometry: slot s = tid; row = s>>3, unit = s&7
    const int srow = tid >> 3;
    const int sgb  = (((tid & 7) ^ (srow & 7)) << 4);

    const bf16* Q  = qh + (size_t)bh * T_LEN * D_K;
    const bf16* K  = kh + (size_t)bh * T_LEN * D_K;
    const bf16* V  = vt + (size_t)bh * D_K * T_LEN;
    const float* NK = nk + (size_t)bh * T_LEN;

    const float al   = alpha[bh & (N_HEADS - 1)];
    const float a4   = al * 4.0f * 1.44269504f;     // into log2 domain
    const float negM = -(al * 1.44269504f) - 1e-4f; // |score|*log2e <= al*log2e

    const bf16x8 bq0 = *(const bf16x8*)&Q[(size_t)myq * D_K + g*8];
    const bf16x8 bq1 = *(const bf16x8*)&Q[(size_t)myq * D_K + 32 + g*8];
    const float nq_own = nq[(size_t)bh * T_LEN + myq];

    bf16x8 ones;
    #pragma unroll
    for (int e = 0; e < 8; e++) ones[e] = (bf16)1.0f;

    f32x4 o[4] = {};    // O^T: lane owns q col; d = f*16 + g*4 + r
    f32x4 o4  = {};     // row-sum accumulator (all r equal)

    // prologue: stage tile 0 into buf 0
    gload16((const bf16*)((const char*)&K[(size_t)srow * D_K] + sgb), &Ks[0][w * 512]);
    gload16((const bf16*)((const char*)&V[(size_t)srow * T_LEN] + sgb), &Vs[0][w * 512]);
    __syncthreads();

    const int NT = T_LEN / KVB;   // 32
    int cur = 0;
    for (int t = 0; t < NT; ++t) {
        const int k0 = t * KVB;
        if (t + 1 < NT) {
            const int kn = k0 + KVB;
            gload16((const bf16*)((const char*)&K[(size_t)(kn + srow) * D_K] + sgb), &Ks[cur^1][w * 512]);
            gload16((const bf16*)((const char*)&V[(size_t)srow * T_LEN + kn] + sgb), &Vs[cur^1][w * 512]);
        }

        // ---- S^T = K.Q^T ----
        f32x4 S[4];
        __builtin_amdgcn_s_setprio(1);
        #pragma unroll
        for (int cb = 0; cb < 4; cb++) {
            const char* kbase = (const char*)&Ks[cur][(size_t)(cb*16 + c) * D_K];
            const bf16x8 ka = *(const bf16x8*)(kbase + ((g*16) ^ sw));
            const bf16x8 kb = *(const bf16x8*)(kbase + ((64 + g*16) ^ sw));
            f32x4 s = {};
            s = __builtin_amdgcn_mfma_f32_16x16x32_bf16(ka, bq0, s, 0, 0, 0);
            s = __builtin_amdgcn_mfma_f32_16x16x32_bf16(kb, bq1, s, 0, 0, 0);
            S[cb] = s;
        }
        __builtin_amdgcn_s_setprio(0);

        // ---- fixed-max softmax: p = exp2(a4*S/den^2 - M), no reductions ----
        #pragma unroll
        for (int cb = 0; cb < 4; cb++) {
            const float4 nk4 = *(const float4*)&NK[k0 + cb*16 + g*4];
            const float nkr[4] = {nk4.x, nk4.y, nk4.z, nk4.w};
            bf16x4 pk;
            #pragma unroll
            for (int r = 0; r < 4; r++) {
                const float den = nq_own + nkr[r];
                const float rr  = __builtin_amdgcn_rcpf(den);
                const float x   = __builtin_fmaf(a4 * S[cb][r], rr * rr, negM);
                pk[r] = (bf16)__builtin_amdgcn_exp2f(x);
            }
            *(bf16x4*)&plds[w][c][cb*16 + g*4] = pk;
        }

        // ---- O^T += V^T . P^T ; row-sum += 1 . P^T ----
        __builtin_amdgcn_s_setprio(1);
        #pragma unroll
        for (int ks = 0; ks < 2; ks++) {
            const bf16x8 pb = *(const bf16x8*)&plds[w][c][ks*32 + g*8];
            #pragma unroll
            for (int f = 0; f < 4; f++) {
                const char* vbase = (const char*)&Vs[cur][(size_t)(f*16 + c) * D_K];
                const bf16x8 vb = *(const bf16x8*)(vbase + ((ks*64 + g*16) ^ sw));
                o[f] = __builtin_amdgcn_mfma_f32_16x16x32_bf16(vb, pb, o[f], 0, 0, 0);
            }
            o4 = __builtin_amdgcn_mfma_f32_16x16x32_bf16(ones, pb, o4, 0, 0, 0);
        }
        __builtin_amdgcn_s_setprio(0);

        __syncthreads();   // drains staging vmcnt + all waves done with cur
        cur ^= 1;
    }

    // ---- epilogue: O[q][d] / rowsum -> ao [B,T,D] bf16 ----
    const int b_ = bh >> 4, h_ = bh & 15;
    const float inv = 1.0f / o4[0];
    #pragma unroll
    for (int f = 0; f < 4; f++) {
        bf16x4 w4;
        #pragma unroll
        for (int r = 0; r < 4; r++) w4[r] = (bf16)(o[f][r] * inv);
        *(bf16x4*)&ao[((size_t)(b_*T_LEN + myq))*D_MODEL + h_*D_K + f*16 + g*4] = w4;
    }
}

// ---------------------------------------------------------------------------
// Final GEMM: out_f32[4096,1024] = ao_bf16 @ WtO^T + bo.  BM=64,BN=128 ->
// grid 512 (2 blocks/CU).
// ---------------------------------------------------------------------------
__global__ __launch_bounds__(256) void gemmo_kernel(
    const bf16* __restrict__ A, const bf16* __restrict__ Bt,
    const float* __restrict__ bias, float* __restrict__ Out)
{
    __shared__ bf16 As[64][32];
    __shared__ bf16 Bs[128][32];

    const int tid = threadIdx.x, lane = tid & 63, w = tid >> 6;
    const int wm = w >> 1, wn = w & 1, g = lane >> 4, c = lane & 15;
    const int m0 = blockIdx.x * 64, n0 = blockIdx.y * 128;

    const int srow = tid >> 2, scol = (tid & 3) * 8;
    const bf16* Ag = A  + (size_t)(m0 + srow) * D_MODEL + scol;
    const bf16* Bg = Bt + (size_t)(n0 + srow) * D_MODEL + scol;
    bf16* Al  = &As[w * 16][0];
    bf16* Bl0 = &Bs[w * 16][0];
    bf16* Bl1 = &Bs[64 + w * 16][0];

    f32x4 acc[2][4] = {};

    for (int k0 = 0; k0 < D_MODEL; k0 += 32) {
        gload16(Ag + k0, Al);
        gload16(Bg + k0, Bl0);
        gload16(Bg + (size_t)64 * D_MODEL + k0, Bl1);
        __syncthreads();

        bf16x8 a[2], b[4];
        #pragma unroll
        for (int i = 0; i < 2; i++) a[i] = *(const bf16x8*)&As[wm*32 + i*16 + c][g*8];
        #pragma unroll
        for (int j = 0; j < 4; j++) b[j] = *(const bf16x8*)&Bs[wn*64 + j*16 + c][g*8];

        __builtin_amdgcn_s_setprio(1);
        #pragma unroll
        for (int i = 0; i < 2; i++)
            #pragma unroll
            for (int j = 0; j < 4; j++)
                acc[i][j] = __builtin_amdgcn_mfma_f32_16x16x32_bf16(a[i], b[j], acc[i][j], 0, 0, 0);
        __builtin_amdgcn_s_setprio(0);
        __syncthreads();
    }

    #pragma unroll
    for (int i = 0; i < 2; i++)
        #pragma unroll
        for (int j = 0; j < 4; j++) {
            const int ncol = n0 + wn*64 + j*16 + c;
            const float bb = bias[ncol];
            #pragma unroll
            for (int r = 0; r < 4; r++) {
                const int mrow = m0 + wm*32 + i*16 + g*4 + r;
                Out[(size_t)mrow * D_MODEL + ncol] = acc[i][j][r] + bb;
            }
        }
}

// ---------------------------------------------------------------------------
extern "C" void kernel_launch(void* const* d_in, const int* in_sizes, int n_in,
                              void* d_out, int out_size, void* d_ws, size_t ws_size,
                              hipStream_t stream) {
    const float* q     = (const float*)d_in[0];
    const float* k     = (const float*)d_in[1];
    const float* v     = (const float*)d_in[2];
    const float* Wq    = (const float*)d_in[3];
    const float* bq    = (const float*)d_in[4];
    const float* Wk    = (const float*)d_in[5];
    const float* bk    = (const float*)d_in[6];
    const float* Wv    = (const float*)d_in[7];
    const float* bv    = (const float*)d_in[8];
    const float* Wo    = (const float*)d_in[9];
    const float* bo    = (const float*)d_in[10];
    const float* alpha = (const float*)d_in[11];

    char* ws = (char*)d_ws;
    const size_t WBYTES = (size_t)D_MODEL * D_MODEL * sizeof(bf16);                // 2MB
    const size_t HBYTES = (size_t)B_SZ * N_HEADS * T_LEN * D_K * sizeof(bf16);     // 8MB
    const size_t NBYTES = (size_t)B_SZ * N_HEADS * T_LEN * sizeof(float);          // 256KB
    bf16* WtQ = (bf16*)ws;  ws += WBYTES;
    bf16* WtK = (bf16*)ws;  ws += WBYTES;
    bf16* WtV = (bf16*)ws;  ws += WBYTES;
    bf16* WtO = (bf16*)ws;  ws += WBYTES;
    bf16* qh  = (bf16*)ws;  ws += HBYTES;
    bf16* kh  = (bf16*)ws;  ws += HBYTES;
    bf16* vt  = (bf16*)ws;  ws += HBYTES;
    float* nq = (float*)ws; ws += NBYTES;
    float* nk = (float*)ws; ws += NBYTES;
    bf16* ao  = (bf16*)ws;  ws += (size_t)M_ROWS * D_MODEL * sizeof(bf16);         // 8MB

    wt_kernel<<<dim3(32, 32, 4), dim3(32, 8), 0, stream>>>(
        Wq, Wk, Wv, Wo, WtQ, WtK, WtV, WtO);

    proj_kernel<<<dim3(32, 8, 3), 256, 0, stream>>>(
        q, k, v, WtQ, WtK, WtV, bq, bk, bv, qh, kh, vt);

    const int nrows = B_SZ * N_HEADS * T_LEN;
    norm_kernel<<<dim3(nrows / 4, 2), 256, 0, stream>>>(qh, kh, nq, nk, nrows);

    attn_kernel<<<512, 512, 0, stream>>>(qh, kh, vt, nq, nk, alpha, ao);

    gemmo_kernel<<<dim3(M_ROWS / 64, D_MODEL / 128), 256, 0, stream>>>(ao, WtO, bo, (float*)d_out);
}